// Round 13
// baseline (211.875 us; speedup 1.0000x reference)
//
#include <hip/hip_runtime.h>
#include <hip/hip_bf16.h>
#include <limits.h>

// ---- problem constants ----
#define NN   40960
#define EE   327680
#define NN1  20480
#define EE2  163840
#define NN2  10240
#define BB   512
#define NCLS 10

// scan geometry: 5 segments (deg1, degS, degD, degC1, degC2)
#define SEG1 160   // deg1: NN/256
#define SEG2 240   // +degS: NN1/256
#define SEG3 320   // +degD
#define SEG4 400   // +degC1
#define SBT  440   // +degC2: NN2/256

// merged-kernel geometry
#define CART_BLKS 640           // EE2/256
#define PREP_BLKS 208           // ceil(13*8*64*8 / 256)

typedef short bf16x8 __attribute__((ext_vector_type(8)));
typedef float f32x4 __attribute__((ext_vector_type(4)));

__device__ __forceinline__ float elu_f(float v) { return v > 0.f ? v : (expf(v) - 1.f); }
__device__ __forceinline__ unsigned f2bf_bits(float v) {  // RNE f32->bf16 bits
    unsigned u = __float_as_uint(v);
    return (u + 0x7FFFu + ((u >> 16) & 1u)) >> 16;
}

// ---- init: zero degree counters + xgsum shards + mBits ----
__global__ void init_all(int* zbase, int zcount) {
    int i = blockIdx.x * 256 + threadIdx.x;
    if (i < zcount) zbase[i] = 0;
}

// ---- degree count WITH slot capture: the one atomic pass ----
__global__ void deg_count(const int* __restrict__ ei, const int* __restrict__ ei2,
                          const int* __restrict__ cluster1, const int* __restrict__ cluster2,
                          int* deg1, int* degS, int* degD, int* degC1, int* degC2,
                          int* slot1, int* slotS, int* slotD, int* slotC1, int* slotC2) {
    int i = blockIdx.x * 256 + threadIdx.x;
    if (i < EE) slot1[i] = atomicAdd(deg1 + ei[EE + i], 1);
    if (i < EE2) {
        slotS[i] = atomicAdd(degS + ei2[i], 1);
        slotD[i] = atomicAdd(degD + ei2[EE2 + i], 1);
    }
    if (i < NN) slotC1[i] = atomicAdd(degC1 + cluster1[i], 1);
    if (i < NN1) slotC2[i] = atomicAdd(degC2 + cluster2[i], 1);
}

// ---- scan step 1: per-block partial sums ----
__global__ __launch_bounds__(256) void scan_partial(
    const int* __restrict__ deg1, const int* __restrict__ degS,
    const int* __restrict__ degD, const int* __restrict__ degC1,
    const int* __restrict__ degC2, int* __restrict__ part) {
    int b = blockIdx.x, t = threadIdx.x;
    const int* src;
    int off;
    if (b < SEG1)      { src = deg1;  off = b * 256; }
    else if (b < SEG2) { src = degS;  off = (b - SEG1) * 256; }
    else if (b < SEG3) { src = degD;  off = (b - SEG2) * 256; }
    else if (b < SEG4) { src = degC1; off = (b - SEG3) * 256; }
    else               { src = degC2; off = (b - SEG4) * 256; }
    int v = src[off + t];
#pragma unroll
    for (int o = 32; o; o >>= 1) v += __shfl_down(v, o, 64);
    __shared__ int sred[4];
    if ((t & 63) == 0) sred[t >> 6] = v;
    __syncthreads();
    if (t == 0) part[b] = sred[0] + sred[1] + sred[2] + sred[3];
}

// ---- scan step 2 (fused base+apply): every block derives its own segment base ----
__global__ __launch_bounds__(256) void scan_apply(
    const int* __restrict__ deg1, const int* __restrict__ degS,
    const int* __restrict__ degD, const int* __restrict__ degC1,
    const int* __restrict__ degC2, const int* __restrict__ part,
    int* rowptr1, int* rowptrS, int* rowptrD, int* rowptrC1, int* rowptrC2) {
    int b = blockIdx.x, t = threadIdx.x;
    const int* src;
    int* rp;
    int off, segLo;
    if (b < SEG1)      { src = deg1;  rp = rowptr1;  off = b * 256;          segLo = 0; }
    else if (b < SEG2) { src = degS;  rp = rowptrS;  off = (b - SEG1) * 256; segLo = SEG1; }
    else if (b < SEG3) { src = degD;  rp = rowptrD;  off = (b - SEG2) * 256; segLo = SEG2; }
    else if (b < SEG4) { src = degC1; rp = rowptrC1; off = (b - SEG3) * 256; segLo = SEG3; }
    else               { src = degC2; rp = rowptrC2; off = (b - SEG4) * 256; segLo = SEG4; }
    // segment-exclusive base = sum part[segLo .. b-1]
    int bs = 0;
    for (int p = segLo + t; p < b; p += 256) bs += part[p];
#pragma unroll
    for (int o = 32; o; o >>= 1) bs += __shfl_down(bs, o, 64);
    __shared__ int sred[4];
    __shared__ int sh[256];
    if ((t & 63) == 0) sred[t >> 6] = bs;
    int v = src[off + t];
    sh[t] = v;
    __syncthreads();
    int base = sred[0] + sred[1] + sred[2] + sred[3];
#pragma unroll
    for (int o = 1; o < 256; o <<= 1) {
        int u = (t >= o) ? sh[t - o] : 0;
        __syncthreads();
        sh[t] += u;
        __syncthreads();
    }
    rp[off + t] = sh[t] - v + base;
    if (b == 0 && t == 0) {
        rowptr1[NN] = EE;
        rowptrS[NN1] = EE2;
        rowptrD[NN1] = EE2;
        rowptrC1[NN1] = NN;
        rowptrC2[NN2] = NN1;
    }
}

// ---- fill (NO atomics): p = rowptr[key] + slot ----
__global__ void fill_csr(const float* __restrict__ x, const float* __restrict__ ea,
                         const int* __restrict__ ei, const int* __restrict__ ei2,
                         const int* __restrict__ cluster1, const int* __restrict__ cluster2,
                         const int* __restrict__ rowptr1, const int* __restrict__ rowptrS,
                         const int* __restrict__ rowptrD, const int* __restrict__ rowptrC1,
                         const int* __restrict__ rowptrC2,
                         const int* __restrict__ slot1, const int* __restrict__ slotS,
                         const int* __restrict__ slotD, const int* __restrict__ slotC1,
                         const int* __restrict__ slotC2,
                         float4* __restrict__ eadj1, int4* __restrict__ cscRec,
                         int* __restrict__ memC1, int* __restrict__ memC2) {
    int i = blockIdx.x * 256 + threadIdx.x;
    if (i < EE) {
        int s = ei[i], d = ei[EE + i];
        eadj1[rowptr1[d] + slot1[i]] = make_float4(x[s], ea[2 * i], ea[2 * i + 1], 0.f);
    }
    if (i < EE2) {
        int s2 = ei2[i], d2 = ei2[EE2 + i];
        int q = rowptrS[s2] + slotS[i];
        int p2 = rowptrD[d2] + slotD[i];
        cscRec[q] = make_int4(s2, d2, p2, 0);
    }
    if (i < NN) memC1[rowptrC1[cluster1[i]] + slotC1[i]] = i;
    if (i < NN1) memC2[rowptrC2[cluster2[i]] + slotC2[i]] = i;
}

// ---- conv1 gather: aggregate-then-matvec; 2-deep prefetch; plain x1 write ----
__global__ __launch_bounds__(256) void conv1_gather(
    const float* __restrict__ x, const int* __restrict__ rowptr1,
    const float4* __restrict__ eadj1,
    const float* __restrict__ w1, const float* __restrict__ b1,
    const float* __restrict__ w2, const float* __restrict__ b2,
    const float* __restrict__ root1, const float* __restrict__ bias1,
    float* __restrict__ x1) {
    int t = threadIdx.x;
    int j = t & 31;
    int n = blockIdx.x * 8 + (t >> 5);
    float w1x = 0.f, w1y = 0.f, b1j = 0.f;
    if (j < 25) { w1x = w1[j]; w1y = w1[25 + j]; b1j = b1[j]; }
    int r0 = rowptr1[n], r1 = rowptr1[n + 1];
    float agg = 0.f, sumx = 0.f;
    float4 e0 = make_float4(0.f, 0.f, 0.f, 0.f), e1 = e0;
    if (r0 < r1) e0 = eadj1[r0];
    if (r0 + 1 < r1) e1 = eadj1[r0 + 1];
    for (int p = r0; p < r1; p++) {
        float4 ed = e0;
        e0 = e1;
        if (p + 2 < r1) e1 = eadj1[p + 2];
        float h = fmaxf(fmaf(ed.y, w1x, fmaf(ed.z, w1y, b1j)), 0.f);
        agg = fmaf(ed.x, h, agg);
        sumx += ed.x;
    }
    float w2c[25];
#pragma unroll
    for (int k = 0; k < 25; k++) w2c[k] = w2[k * 32 + j];
    float m = sumx * b2[j];
#pragma unroll
    for (int k = 0; k < 25; k++) m = fmaf(__shfl(agg, k, 32), w2c[k], m);
    float deg = fmaxf((float)(r1 - r0), 1.f);
    float v = fmaf(x[n], root1[j], m / deg + bias1[j]);
    x1[(size_t)n * 32 + j] = elu_f(v);
}

// ---- pool1 gather: per cluster max/mean/batch + bf16 x1p write ----
__global__ __launch_bounds__(256) void pool1_gather(
    const float* __restrict__ x1, const float* __restrict__ pos,
    const int* __restrict__ batch, const int* __restrict__ rowptrC1,
    const int* __restrict__ memC1,
    float* __restrict__ x1p, unsigned short* __restrict__ x1pb,
    float* __restrict__ pos1, int* __restrict__ batch1) {
    int t = threadIdx.x;
    int j = t & 31;
    int c = blockIdx.x * 8 + (t >> 5);
    int r0 = rowptrC1[c], r1 = rowptrC1[c + 1];
    float mx = -INFINITY, sx = 0.f, sy = 0.f;
    int bmax = INT_MIN;
    for (int p = r0; p < r1; p++) {
        int v = memC1[p];
        mx = fmaxf(mx, x1[(size_t)v * 32 + j]);
        bmax = max(bmax, batch[v]);
        if (j == 0) {
            float2 pv = ((const float2*)pos)[v];
            sx += pv.x; sy += pv.y;
        }
    }
    float outv = (r0 < r1) ? mx : 0.f;
    x1p[(size_t)c * 32 + j] = outv;
    x1pb[(size_t)c * 32 + j] = (unsigned short)f2bf_bits(outv);
    if (j == 0) {
        float cn = fmaxf((float)(r1 - r0), 1.f);
        pos1[2 * c] = sx / cn;
        pos1[2 * c + 1] = sy / cn;
        batch1[c] = min(max(bmax, 0), BB - 1);
    }
}

// ---- merged: global max |cart| (blocks 0..639) + Wext B-fragment prep (640..847) ----
__global__ void cartmax_prep(const float* __restrict__ pos1, const int* __restrict__ ei2,
                             unsigned* mBits,
                             const float* __restrict__ w2, const float* __restrict__ b2,
                             unsigned short* __restrict__ WextB) {
    int b = blockIdx.x;
    int t = threadIdx.x;
    if (b < CART_BLKS) {
        int e = b * 256 + t;
        float m = 0.f;
        if (e < EE2) {
            int r = ei2[e], c = ei2[EE2 + e];
            m = fmaxf(fabsf(pos1[2 * r] - pos1[2 * c]),
                      fabsf(pos1[2 * r + 1] - pos1[2 * c + 1]));
        }
        for (int off = 32; off; off >>= 1) m = fmaxf(m, __shfl_xor(m, off, 64));
        if ((t & 63) == 0) atomicMax(mBits, __float_as_uint(m));
    } else {
        int idx = (b - CART_BLKS) * 256 + t;
        if (idx >= 13 * 8 * 64 * 8) return;
        int j = idx & 7;
        int lane = (idx >> 3) & 63;
        int tile = (idx >> 9) & 7;
        int ky = idx >> 12;
        int h = tile >> 2, tt = tile & 3;
        int kmlp = 2 * ky + h;
        int o = tt * 16 + (lane & 15);
        int i = (lane >> 4) * 8 + j;
        float v = (kmlp < 25) ? w2[(size_t)kmlp * 2048 + i * 64 + o] : b2[i * 64 + o];
        WextB[idx] = (unsigned short)f2bf_bits(v);
    }
}

// ---- per-edge packed bf16 r-vectors (64B rows, dstSlot embedded at [13]) ----
__global__ __launch_bounds__(256) void r2_kernel(
    const int4* __restrict__ cscRec, const float* __restrict__ pos1,
    const float* __restrict__ w1, const float* __restrict__ b1,
    const unsigned* __restrict__ mBits, uint4* __restrict__ r2q) {
    int q = blockIdx.x * 256 + threadIdx.x;
    if (q >= EE2) return;
    int4 rec = cscRec[q];
    int s = rec.x, d = rec.y;
    float inv = 0.5f / __uint_as_float(*mBits);
    float2 ps = ((const float2*)pos1)[s];
    float2 pd = ((const float2*)pos1)[d];
    float cx = fmaf(ps.x - pd.x, inv, 0.5f);
    float cy = fmaf(ps.y - pd.y, inv, 0.5f);
    unsigned out[16];
#pragma unroll
    for (int ky = 0; ky < 13; ky++) {
        int k0 = 2 * ky, k1 = 2 * ky + 1;
        float rlo = fmaxf(fmaf(cx, w1[k0], fmaf(cy, w1[25 + k0], b1[k0])), 0.f);
        float rhi = 1.f;
        if (k1 < 25) rhi = fmaxf(fmaf(cx, w1[k1], fmaf(cy, w1[25 + k1], b1[k1])), 0.f);
        out[ky] = f2bf_bits(rlo) | (f2bf_bits(rhi) << 16);
    }
    out[13] = (unsigned)rec.z;  // dest-order slot
    out[14] = 0u; out[15] = 0u;
    uint4* dst = r2q + (size_t)q * 4;
    dst[0] = make_uint4(out[0], out[1], out[2], out[3]);
    dst[1] = make_uint4(out[4], out[5], out[6], out[7]);
    dst[2] = make_uint4(out[8], out[9], out[10], out[11]);
    dst[3] = make_uint4(out[12], out[13], out[14], out[15]);
}

// ---- conv2 FUSED: MFMA A-tile (16 srcs) into LDS, then per-src edge messages ----
// Stage 1: 4 waves compute 13 ky planes of A[16 rows][1664 cols] as packed bf16 pairs
// Stage 2: wave w processes srcs s0+4w..s0+4w+3; 13 LDS reads + 26 FMA per edge
__global__ __launch_bounds__(256) void conv2_fused(
    const unsigned short* __restrict__ x1pb, const unsigned short* __restrict__ WextB,
    const uint4* __restrict__ r2q, const int* __restrict__ rowptrS,
    unsigned short* __restrict__ msgbuf) {
    __shared__ unsigned lau[16 * 833];  // [row][833] u32, +1 pad vs 832
    int t = threadIdx.x;
    int lane = t & 63;
    int w = t >> 6;
    int s0 = blockIdx.x * 16;
    int lo16 = lane & 15, hi4 = lane >> 4;
    // ---- stage 1: A rows for srcs s0..s0+15 (same fragment mapping as a_gemm_mfma) ----
    bf16x8 af = *(const bf16x8*)(x1pb + ((size_t)(s0 + lo16) * 32 + hi4 * 8));
    const f32x4 zero = {0.f, 0.f, 0.f, 0.f};
    for (int ky = w; ky < 13; ky += 4) {
        const bf16x8* Bp = (const bf16x8*)(WextB + (size_t)ky * 4096);
        f32x4 acc[8];
#pragma unroll
        for (int i = 0; i < 8; i++) {
            bf16x8 bf = Bp[i * 64 + lane];
            acc[i] = __builtin_amdgcn_mfma_f32_16x16x32_bf16(af, bf, zero, 0, 0, 0);
        }
#pragma unroll
        for (int tt = 0; tt < 4; tt++) {
#pragma unroll
            for (int j = 0; j < 4; j++) {
                int row = hi4 * 4 + j;
                unsigned lo = f2bf_bits(acc[tt][j]);
                unsigned hi = f2bf_bits(acc[4 + tt][j]);
                lau[row * 833 + ky * 64 + tt * 16 + lo16] = lo | (hi << 16);
            }
        }
    }
    __syncthreads();
    // ---- stage 2: each wave processes 4 srcs ----
    for (int si = 0; si < 4; si++) {
        int sl = w * 4 + si;
        int s = s0 + sl;
        int r0 = rowptrS[s], r1 = rowptrS[s + 1];
        const unsigned* la = lau + sl * 833;
        uint4 A0, B0, C0, D0;
        if (r0 < r1) {
            const uint4* p4 = r2q + (size_t)r0 * 4;
            A0 = p4[0]; B0 = p4[1]; C0 = p4[2]; D0 = p4[3];
        }
        for (int q = r0; q < r1; q++) {
            uint4 a = A0, b = B0, c = C0, dd = D0;
            if (q + 1 < r1) {
                const uint4* p4 = r2q + (size_t)(q + 1) * 4;
                A0 = p4[0]; B0 = p4[1]; C0 = p4[2]; D0 = p4[3];
            }
            unsigned rr[13] = {a.x, a.y, a.z, a.w, b.x, b.y, b.z, b.w,
                               c.x, c.y, c.z, c.w, dd.x};
            unsigned dstSlot = dd.y;
            float m0 = 0.f, m1 = 0.f;
#pragma unroll
            for (int ky = 0; ky < 13; ky++) {
                unsigned rp = rr[ky];
                unsigned ua = la[ky * 64 + lane];
                m0 = fmaf(__uint_as_float(rp << 16), __uint_as_float(ua << 16), m0);
                m1 = fmaf(__uint_as_float(rp & 0xFFFF0000u), __uint_as_float(ua & 0xFFFF0000u), m1);
            }
            msgbuf[(size_t)dstSlot * 64 + lane] = (unsigned short)f2bf_bits(m0 + m1);
        }
    }
}

// ---- conv2 phase 2: per-dest STREAMING sum + fused x2 ----
__global__ __launch_bounds__(256) void conv2_fin(
    const unsigned short* __restrict__ msgbuf, const int* __restrict__ rowptrD,
    const float* __restrict__ x1p, const float* __restrict__ root2,
    const float* __restrict__ bias2, float* __restrict__ x2) {
    int t = threadIdx.x;
    int lane = t & 63;
    int n = blockIdx.x * 4 + (t >> 6);
    float Rr[32];
#pragma unroll
    for (int i = 0; i < 32; i++) Rr[i] = root2[i * 64 + lane];
    int r0 = rowptrD[n], r1 = rowptrD[n + 1];
    float acc = 0.f;
    for (int p = r0; p < r1; p++)
        acc += __uint_as_float((unsigned)msgbuf[(size_t)p * 64 + lane] << 16);
    float deg = fmaxf((float)(r1 - r0), 1.f);
    float xv = x1p[(size_t)n * 32 + (lane & 31)];
    float ra2 = bias2[lane];
#pragma unroll
    for (int i = 0; i < 32; i++) ra2 = fmaf(__shfl(xv, i, 64), Rr[i], ra2);
    x2[(size_t)n * 64 + lane] = elu_f(ra2 + acc / deg);
}

// ---- pool2 gather + fused xg accumulation (8-way sharded atomics) ----
__global__ __launch_bounds__(256) void pool2_gather(
    const float* __restrict__ x2, const int* __restrict__ rowptrC2,
    const int* __restrict__ memC2, const int* __restrict__ batch1,
    float* __restrict__ xgsumS, float* __restrict__ gcntS) {
    int t = threadIdx.x;
    int lane = t & 63;
    int n2 = blockIdx.x * 4 + (t >> 6);
    int r0 = rowptrC2[n2], r1 = rowptrC2[n2 + 1];
    float mx = -INFINITY;
    int bmax = INT_MIN;
    for (int p = r0; p < r1; p++) {
        int m = memC2[p];
        mx = fmaxf(mx, x2[(size_t)m * 64 + lane]);
        bmax = max(bmax, batch1[m]);
    }
    float v = (r0 < r1) ? mx : 0.f;
    int b = min(max(bmax, 0), BB - 1);
    int shard = n2 & 7;
    atomicAdd(xgsumS + ((size_t)shard * BB + b) * 64 + lane, v);
    if (lane == 0) atomicAdd(gcntS + shard * BB + b, 1.f);
}

// ---- head: sum shards -> mean -> fc1+elu -> fc2 -> log_softmax ----
__global__ __launch_bounds__(128) void head_kernel(
    const float* __restrict__ xgsumS, const float* __restrict__ gcntS,
    const float* __restrict__ fc1w, const float* __restrict__ fc1b,
    const float* __restrict__ fc2w, const float* __restrict__ fc2b,
    float* __restrict__ out) {
    int b = blockIdx.x;
    int t = threadIdx.x;
    __shared__ float xg[64];
    __shared__ float h[128];
    __shared__ float lg[NCLS];
    __shared__ float red[2];
    __shared__ float cntsh;
    float s = 0.f;
    if (t < 64) {
#pragma unroll
        for (int sh = 0; sh < 8; sh++) s += xgsumS[((size_t)sh * BB + b) * 64 + t];
    }
    if (t == 64) {
        float c = 0.f;
#pragma unroll
        for (int sh = 0; sh < 8; sh++) c += gcntS[sh * BB + b];
        cntsh = fmaxf(c, 1.f);
    }
    __syncthreads();
    if (t < 64) xg[t] = s / cntsh;
    __syncthreads();
    float a1 = fc1b[t];
    for (int i = 0; i < 64; i++) a1 = fmaf(xg[i], fc1w[i * 128 + t], a1);
    h[t] = elu_f(a1);
    __syncthreads();
    if (t < NCLS) {
        float a = fc2b[t];
        for (int j = 0; j < 128; j++) a = fmaf(h[j], fc2w[j * NCLS + t], a);
        lg[t] = a;
    }
    __syncthreads();
    if (t == 0) {
        float mx = lg[0];
        for (int i = 1; i < NCLS; i++) mx = fmaxf(mx, lg[i]);
        float se = 0.f;
        for (int i = 0; i < NCLS; i++) se += expf(lg[i] - mx);
        red[0] = mx;
        red[1] = logf(se);
    }
    __syncthreads();
    if (t < NCLS) out[(size_t)b * NCLS + t] = lg[t] - red[0] - red[1];
}

extern "C" void kernel_launch(void* const* d_in, const int* in_sizes, int n_in,
                              void* d_out, int out_size, void* d_ws, size_t ws_size,
                              hipStream_t stream) {
    const float* x = (const float*)d_in[0];
    const float* pos = (const float*)d_in[1];
    const float* edge_attr = (const float*)d_in[2];
    const int* ei = (const int*)d_in[3];
    const int* batch = (const int*)d_in[4];
    const int* cluster1 = (const int*)d_in[5];
    const int* ei2 = (const int*)d_in[6];
    const int* cluster2 = (const int*)d_in[7];
    const float* nn1_w1 = (const float*)d_in[8];
    const float* nn1_b1 = (const float*)d_in[9];
    const float* nn1_w2 = (const float*)d_in[10];
    const float* nn1_b2 = (const float*)d_in[11];
    const float* root1 = (const float*)d_in[12];
    const float* bias1 = (const float*)d_in[13];
    const float* nn2_w1 = (const float*)d_in[14];
    const float* nn2_b1 = (const float*)d_in[15];
    const float* nn2_w2 = (const float*)d_in[16];
    const float* nn2_b2 = (const float*)d_in[17];
    const float* root2 = (const float*)d_in[18];
    const float* bias2 = (const float*)d_in[19];
    const float* fc1w = (const float*)d_in[20];
    const float* fc1b = (const float*)d_in[21];
    const float* fc2w = (const float*)d_in[22];
    const float* fc2b = (const float*)d_in[23];

    float* ws = (float*)d_ws;
    // ---- workspace layout (float units; all blocks 16B-aligned) ----
    constexpr size_t OFF_DEG1 = 0;                                 // NN
    constexpr size_t OFF_DEGS = OFF_DEG1 + NN;                     // NN1
    constexpr size_t OFF_DEGD = OFF_DEGS + NN1;                    // NN1
    constexpr size_t OFF_DEGC1 = OFF_DEGD + NN1;                   // NN1
    constexpr size_t OFF_DEGC2 = OFF_DEGC1 + NN1;                  // NN2
    constexpr size_t OFF_XGS = OFF_DEGC2 + NN2;                    // 8*BB*64
    constexpr size_t OFF_GCS = OFF_XGS + (size_t)8 * BB * 64;      // 8*BB
    constexpr size_t OFF_MBITS = OFF_GCS + 8 * BB;                 // 4 (padded)
    constexpr size_t ZTOT = OFF_MBITS + 4;                         // zero region end
    constexpr size_t OFF_PART = ZTOT;                              // SBT
    constexpr size_t OFF_ROWPTR1 = OFF_PART + SBT;                 // NN+4
    constexpr size_t OFF_ROWPTRS = OFF_ROWPTR1 + NN + 4;           // NN1+4
    constexpr size_t OFF_ROWPTRD = OFF_ROWPTRS + NN1 + 4;          // NN1+4
    constexpr size_t OFF_ROWPTRC1 = OFF_ROWPTRD + NN1 + 4;         // NN1+4
    constexpr size_t OFF_ROWPTRC2 = OFF_ROWPTRC1 + NN1 + 4;        // NN2+4
    constexpr size_t OFF_SLOT1 = OFF_ROWPTRC2 + NN2 + 4;           // EE
    constexpr size_t OFF_SLOTS = OFF_SLOT1 + EE;                   // EE2
    constexpr size_t OFF_SLOTD = OFF_SLOTS + EE2;                  // EE2
    constexpr size_t OFF_SLOTC1 = OFF_SLOTD + EE2;                 // NN
    constexpr size_t OFF_SLOTC2 = OFF_SLOTC1 + NN;                 // NN1
    constexpr size_t OFF_CSCREC = OFF_SLOTC2 + NN1;                // EE2*4 (int4)
    constexpr size_t OFF_MEMC1 = OFF_CSCREC + (size_t)EE2 * 4;     // NN
    constexpr size_t OFF_MEMC2 = OFF_MEMC1 + NN;                   // NN1
    constexpr size_t OFF_X1 = OFF_MEMC2 + NN1;                     // NN*32
    constexpr size_t OFF_X1P = OFF_X1 + (size_t)NN * 32;           // NN1*32
    constexpr size_t OFF_X1PB = OFF_X1P + (size_t)NN1 * 32;        // NN1*16 (ushort NN1*32)
    constexpr size_t OFF_POS1 = OFF_X1PB + (size_t)NN1 * 16;       // NN1*2
    constexpr size_t OFF_BATCH1 = OFF_POS1 + (size_t)NN1 * 2;      // NN1
    constexpr size_t OFF_X2 = OFF_BATCH1 + NN1;                    // NN1*64
    constexpr size_t OFF_WEXTB = OFF_X2 + (size_t)NN1 * 64;        // 26624 (ushort 13*8*64*8)
    constexpr size_t OFF_UA = OFF_WEXTB + 26624;                   // union: eadj1 EE*4 / r2q EE2*16
    constexpr size_t UASZ = (size_t)EE2 * 16;                      // 2.62M >= EE*4
    constexpr size_t OFF_MSG = OFF_UA + UASZ;                      // EE2*32 (ushort EE2*64)

    int* deg1 = (int*)(ws + OFF_DEG1);
    int* degS = (int*)(ws + OFF_DEGS);
    int* degD = (int*)(ws + OFF_DEGD);
    int* degC1 = (int*)(ws + OFF_DEGC1);
    int* degC2 = (int*)(ws + OFF_DEGC2);
    float* xgsumS = ws + OFF_XGS;
    float* gcntS = ws + OFF_GCS;
    unsigned* mBits = (unsigned*)(ws + OFF_MBITS);
    int* part = (int*)(ws + OFF_PART);
    int* rowptr1 = (int*)(ws + OFF_ROWPTR1);
    int* rowptrS = (int*)(ws + OFF_ROWPTRS);
    int* rowptrD = (int*)(ws + OFF_ROWPTRD);
    int* rowptrC1 = (int*)(ws + OFF_ROWPTRC1);
    int* rowptrC2 = (int*)(ws + OFF_ROWPTRC2);
    int* slot1 = (int*)(ws + OFF_SLOT1);
    int* slotS = (int*)(ws + OFF_SLOTS);
    int* slotD = (int*)(ws + OFF_SLOTD);
    int* slotC1 = (int*)(ws + OFF_SLOTC1);
    int* slotC2 = (int*)(ws + OFF_SLOTC2);
    int4* cscRec = (int4*)(ws + OFF_CSCREC);
    int* memC1 = (int*)(ws + OFF_MEMC1);
    int* memC2 = (int*)(ws + OFF_MEMC2);
    float* x1 = ws + OFF_X1;
    float* x1p = ws + OFF_X1P;
    unsigned short* x1pb = (unsigned short*)(ws + OFF_X1PB);
    float* pos1 = ws + OFF_POS1;
    int* batch1 = (int*)(ws + OFF_BATCH1);
    float* x2 = ws + OFF_X2;
    unsigned short* WextB = (unsigned short*)(ws + OFF_WEXTB);
    float4* eadj1 = (float4*)(ws + OFF_UA);
    uint4* r2q = (uint4*)(ws + OFF_UA);
    unsigned short* msgbuf = (unsigned short*)(ws + OFF_MSG);

    init_all<<<(int)((ZTOT + 255) / 256), 256, 0, stream>>>((int*)d_ws, (int)ZTOT);
    deg_count<<<EE / 256, 256, 0, stream>>>(ei, ei2, cluster1, cluster2,
                                            deg1, degS, degD, degC1, degC2,
                                            slot1, slotS, slotD, slotC1, slotC2);
    scan_partial<<<SBT, 256, 0, stream>>>(deg1, degS, degD, degC1, degC2, part);
    scan_apply<<<SBT, 256, 0, stream>>>(deg1, degS, degD, degC1, degC2, part,
                                        rowptr1, rowptrS, rowptrD, rowptrC1, rowptrC2);
    fill_csr<<<EE / 256, 256, 0, stream>>>(x, edge_attr, ei, ei2, cluster1, cluster2,
                                           rowptr1, rowptrS, rowptrD, rowptrC1, rowptrC2,
                                           slot1, slotS, slotD, slotC1, slotC2,
                                           eadj1, cscRec, memC1, memC2);
    conv1_gather<<<NN / 8, 256, 0, stream>>>(x, rowptr1, eadj1,
                                             nn1_w1, nn1_b1, nn1_w2, nn1_b2, root1, bias1, x1);
    pool1_gather<<<NN1 / 8, 256, 0, stream>>>(x1, pos, batch, rowptrC1, memC1,
                                              x1p, x1pb, pos1, batch1);
    cartmax_prep<<<CART_BLKS + PREP_BLKS, 256, 0, stream>>>(pos1, ei2, mBits,
                                                            nn2_w2, nn2_b2, WextB);
    r2_kernel<<<EE2 / 256, 256, 0, stream>>>(cscRec, pos1, nn2_w1, nn2_b1, mBits, r2q);
    conv2_fused<<<NN1 / 16, 256, 0, stream>>>(x1pb, WextB, r2q, rowptrS, msgbuf);
    conv2_fin<<<NN1 / 4, 256, 0, stream>>>(msgbuf, rowptrD, x1p, root2, bias2, x2);
    pool2_gather<<<NN2 / 4, 256, 0, stream>>>(x2, rowptrC2, memC2, batch1, xgsumS, gcntS);
    head_kernel<<<BB, 128, 0, stream>>>(xgsumS, gcntS, fc1w, fc1b, fc2w, fc2b,
                                        (float*)d_out);
}

// Round 14
// 200.188 us; speedup vs baseline: 1.0584x; 1.0584x over previous
//
#include <hip/hip_runtime.h>
#include <hip/hip_bf16.h>
#include <limits.h>

// ---- problem constants ----
#define NN   40960
#define EE   327680
#define NN1  20480
#define EE2  163840
#define NN2  10240
#define BB   512
#define NCLS 10

// scan geometry: 5 segments (deg1, degS, degD, degC1, degC2)
#define SEG1 160   // deg1: NN/256
#define SEG2 240   // +degS: NN1/256
#define SEG3 320   // +degD
#define SEG4 400   // +degC1
#define SBT  440   // +degC2: NN2/256

// merged-kernel geometry
#define GEMM_BLKS 2080          // (NN1/128) * 13
#define R2_BLKS   640           // EE2/256
#define CART_BLKS 640           // EE2/256
#define PREP_BLKS 208           // ceil(13*8*64*8 / 256)

typedef short bf16x8 __attribute__((ext_vector_type(8)));
typedef float f32x4 __attribute__((ext_vector_type(4)));

__device__ __forceinline__ float elu_f(float v) { return v > 0.f ? v : (expf(v) - 1.f); }
__device__ __forceinline__ unsigned f2bf_bits(float v) {  // RNE f32->bf16 bits
    unsigned u = __float_as_uint(v);
    return (u + 0x7FFFu + ((u >> 16) & 1u)) >> 16;
}

// ---- init: zero degree counters + xgsum shards + mBits ----
__global__ void init_all(int* zbase, int zcount) {
    int i = blockIdx.x * 256 + threadIdx.x;
    if (i < zcount) zbase[i] = 0;
}

// ---- degree count WITH slot capture: the one atomic pass ----
__global__ void deg_count(const int* __restrict__ ei, const int* __restrict__ ei2,
                          const int* __restrict__ cluster1, const int* __restrict__ cluster2,
                          int* deg1, int* degS, int* degD, int* degC1, int* degC2,
                          int* slot1, int* slotS, int* slotD, int* slotC1, int* slotC2) {
    int i = blockIdx.x * 256 + threadIdx.x;
    if (i < EE) slot1[i] = atomicAdd(deg1 + ei[EE + i], 1);
    if (i < EE2) {
        slotS[i] = atomicAdd(degS + ei2[i], 1);
        slotD[i] = atomicAdd(degD + ei2[EE2 + i], 1);
    }
    if (i < NN) slotC1[i] = atomicAdd(degC1 + cluster1[i], 1);
    if (i < NN1) slotC2[i] = atomicAdd(degC2 + cluster2[i], 1);
}

// ---- scan step 1: per-block partial sums ----
__global__ __launch_bounds__(256) void scan_partial(
    const int* __restrict__ deg1, const int* __restrict__ degS,
    const int* __restrict__ degD, const int* __restrict__ degC1,
    const int* __restrict__ degC2, int* __restrict__ part) {
    int b = blockIdx.x, t = threadIdx.x;
    const int* src;
    int off;
    if (b < SEG1)      { src = deg1;  off = b * 256; }
    else if (b < SEG2) { src = degS;  off = (b - SEG1) * 256; }
    else if (b < SEG3) { src = degD;  off = (b - SEG2) * 256; }
    else if (b < SEG4) { src = degC1; off = (b - SEG3) * 256; }
    else               { src = degC2; off = (b - SEG4) * 256; }
    int v = src[off + t];
#pragma unroll
    for (int o = 32; o; o >>= 1) v += __shfl_down(v, o, 64);
    __shared__ int sred[4];
    if ((t & 63) == 0) sred[t >> 6] = v;
    __syncthreads();
    if (t == 0) part[b] = sred[0] + sred[1] + sred[2] + sred[3];
}

// ---- scan step 2 (fused base+apply): every block derives its own segment base ----
__global__ __launch_bounds__(256) void scan_apply(
    const int* __restrict__ deg1, const int* __restrict__ degS,
    const int* __restrict__ degD, const int* __restrict__ degC1,
    const int* __restrict__ degC2, const int* __restrict__ part,
    int* rowptr1, int* rowptrS, int* rowptrD, int* rowptrC1, int* rowptrC2) {
    int b = blockIdx.x, t = threadIdx.x;
    const int* src;
    int* rp;
    int off, segLo;
    if (b < SEG1)      { src = deg1;  rp = rowptr1;  off = b * 256;          segLo = 0; }
    else if (b < SEG2) { src = degS;  rp = rowptrS;  off = (b - SEG1) * 256; segLo = SEG1; }
    else if (b < SEG3) { src = degD;  rp = rowptrD;  off = (b - SEG2) * 256; segLo = SEG2; }
    else if (b < SEG4) { src = degC1; rp = rowptrC1; off = (b - SEG3) * 256; segLo = SEG3; }
    else               { src = degC2; rp = rowptrC2; off = (b - SEG4) * 256; segLo = SEG4; }
    // segment-exclusive base = sum part[segLo .. b-1]
    int bs = 0;
    for (int p = segLo + t; p < b; p += 256) bs += part[p];
#pragma unroll
    for (int o = 32; o; o >>= 1) bs += __shfl_down(bs, o, 64);
    __shared__ int sred[4];
    __shared__ int sh[256];
    if ((t & 63) == 0) sred[t >> 6] = bs;
    int v = src[off + t];
    sh[t] = v;
    __syncthreads();
    int base = sred[0] + sred[1] + sred[2] + sred[3];
#pragma unroll
    for (int o = 1; o < 256; o <<= 1) {
        int u = (t >= o) ? sh[t - o] : 0;
        __syncthreads();
        sh[t] += u;
        __syncthreads();
    }
    rp[off + t] = sh[t] - v + base;
    if (b == 0 && t == 0) {
        rowptr1[NN] = EE;
        rowptrS[NN1] = EE2;
        rowptrD[NN1] = EE2;
        rowptrC1[NN1] = NN;
        rowptrC2[NN2] = NN1;
    }
}

// ---- fill (NO atomics): p = rowptr[key] + slot ----
__global__ void fill_csr(const float* __restrict__ x, const float* __restrict__ ea,
                         const int* __restrict__ ei, const int* __restrict__ ei2,
                         const int* __restrict__ cluster1, const int* __restrict__ cluster2,
                         const int* __restrict__ rowptr1, const int* __restrict__ rowptrS,
                         const int* __restrict__ rowptrD, const int* __restrict__ rowptrC1,
                         const int* __restrict__ rowptrC2,
                         const int* __restrict__ slot1, const int* __restrict__ slotS,
                         const int* __restrict__ slotD, const int* __restrict__ slotC1,
                         const int* __restrict__ slotC2,
                         float4* __restrict__ eadj1, int4* __restrict__ cscRec,
                         int* __restrict__ memC1, int* __restrict__ memC2) {
    int i = blockIdx.x * 256 + threadIdx.x;
    if (i < EE) {
        int s = ei[i], d = ei[EE + i];
        eadj1[rowptr1[d] + slot1[i]] = make_float4(x[s], ea[2 * i], ea[2 * i + 1], 0.f);
    }
    if (i < EE2) {
        int s2 = ei2[i], d2 = ei2[EE2 + i];
        int q = rowptrS[s2] + slotS[i];
        int p2 = rowptrD[d2] + slotD[i];
        cscRec[q] = make_int4(s2, d2, p2, 0);
    }
    if (i < NN) memC1[rowptrC1[cluster1[i]] + slotC1[i]] = i;
    if (i < NN1) memC2[rowptrC2[cluster2[i]] + slotC2[i]] = i;
}

// ---- conv1 gather: aggregate-then-matvec; 2-deep prefetch; plain x1 write ----
__global__ __launch_bounds__(256) void conv1_gather(
    const float* __restrict__ x, const int* __restrict__ rowptr1,
    const float4* __restrict__ eadj1,
    const float* __restrict__ w1, const float* __restrict__ b1,
    const float* __restrict__ w2, const float* __restrict__ b2,
    const float* __restrict__ root1, const float* __restrict__ bias1,
    float* __restrict__ x1) {
    int t = threadIdx.x;
    int j = t & 31;
    int n = blockIdx.x * 8 + (t >> 5);
    float w1x = 0.f, w1y = 0.f, b1j = 0.f;
    if (j < 25) { w1x = w1[j]; w1y = w1[25 + j]; b1j = b1[j]; }
    int r0 = rowptr1[n], r1 = rowptr1[n + 1];
    float agg = 0.f, sumx = 0.f;
    float4 e0 = make_float4(0.f, 0.f, 0.f, 0.f), e1 = e0;
    if (r0 < r1) e0 = eadj1[r0];
    if (r0 + 1 < r1) e1 = eadj1[r0 + 1];
    for (int p = r0; p < r1; p++) {
        float4 ed = e0;
        e0 = e1;
        if (p + 2 < r1) e1 = eadj1[p + 2];
        float h = fmaxf(fmaf(ed.y, w1x, fmaf(ed.z, w1y, b1j)), 0.f);
        agg = fmaf(ed.x, h, agg);
        sumx += ed.x;
    }
    float w2c[25];
#pragma unroll
    for (int k = 0; k < 25; k++) w2c[k] = w2[k * 32 + j];
    float m = sumx * b2[j];
#pragma unroll
    for (int k = 0; k < 25; k++) m = fmaf(__shfl(agg, k, 32), w2c[k], m);
    float deg = fmaxf((float)(r1 - r0), 1.f);
    float v = fmaf(x[n], root1[j], m / deg + bias1[j]);
    x1[(size_t)n * 32 + j] = elu_f(v);
}

// ---- pool1 gather: per cluster max/mean/batch + bf16 x1p write ----
__global__ __launch_bounds__(256) void pool1_gather(
    const float* __restrict__ x1, const float* __restrict__ pos,
    const int* __restrict__ batch, const int* __restrict__ rowptrC1,
    const int* __restrict__ memC1,
    float* __restrict__ x1p, unsigned short* __restrict__ x1pb,
    float* __restrict__ pos1, int* __restrict__ batch1) {
    int t = threadIdx.x;
    int j = t & 31;
    int c = blockIdx.x * 8 + (t >> 5);
    int r0 = rowptrC1[c], r1 = rowptrC1[c + 1];
    float mx = -INFINITY, sx = 0.f, sy = 0.f;
    int bmax = INT_MIN;
    for (int p = r0; p < r1; p++) {
        int v = memC1[p];
        mx = fmaxf(mx, x1[(size_t)v * 32 + j]);
        bmax = max(bmax, batch[v]);
        if (j == 0) {
            float2 pv = ((const float2*)pos)[v];
            sx += pv.x; sy += pv.y;
        }
    }
    float outv = (r0 < r1) ? mx : 0.f;
    x1p[(size_t)c * 32 + j] = outv;
    x1pb[(size_t)c * 32 + j] = (unsigned short)f2bf_bits(outv);
    if (j == 0) {
        float cn = fmaxf((float)(r1 - r0), 1.f);
        pos1[2 * c] = sx / cn;
        pos1[2 * c + 1] = sy / cn;
        batch1[c] = min(max(bmax, 0), BB - 1);
    }
}

// ---- merged: global max |cart| (blocks 0..639) + Wext B-fragment prep (640..847) ----
__global__ void cartmax_prep(const float* __restrict__ pos1, const int* __restrict__ ei2,
                             unsigned* mBits,
                             const float* __restrict__ w2, const float* __restrict__ b2,
                             unsigned short* __restrict__ WextB) {
    int b = blockIdx.x;
    int t = threadIdx.x;
    if (b < CART_BLKS) {
        int e = b * 256 + t;
        float m = 0.f;
        if (e < EE2) {
            int r = ei2[e], c = ei2[EE2 + e];
            m = fmaxf(fabsf(pos1[2 * r] - pos1[2 * c]),
                      fabsf(pos1[2 * r + 1] - pos1[2 * c + 1]));
        }
        for (int off = 32; off; off >>= 1) m = fmaxf(m, __shfl_xor(m, off, 64));
        if ((t & 63) == 0) atomicMax(mBits, __float_as_uint(m));
    } else {
        int idx = (b - CART_BLKS) * 256 + t;
        if (idx >= 13 * 8 * 64 * 8) return;
        int j = idx & 7;
        int lane = (idx >> 3) & 63;
        int tile = (idx >> 9) & 7;
        int ky = idx >> 12;
        int h = tile >> 2, tt = tile & 3;
        int kmlp = 2 * ky + h;
        int o = tt * 16 + (lane & 15);
        int i = (lane >> 4) * 8 + j;
        float v = (kmlp < 25) ? w2[(size_t)kmlp * 2048 + i * 64 + o] : b2[i * 64 + o];
        WextB[idx] = (unsigned short)f2bf_bits(v);
    }
}

// ---- merged: MFMA A-GEMM (blocks 0..2079) + r2 edge vectors (2080..2719) ----
__global__ __launch_bounds__(256) void gemm_r2(
    const unsigned short* __restrict__ x1pb, const unsigned short* __restrict__ WextB,
    unsigned* __restrict__ Au,
    const int4* __restrict__ cscRec, const float* __restrict__ pos1,
    const float* __restrict__ w1, const float* __restrict__ b1,
    const unsigned* __restrict__ mBits, uint4* __restrict__ r2q) {
    int blk = blockIdx.x;
    int t = threadIdx.x;
    if (blk < GEMM_BLKS) {
        int lane = t & 63;
        int w = t >> 6;
        int bx = blk % 160;
        int ky = blk / 160;
        int m0 = bx * 128 + w * 32;
        int lo16 = lane & 15, hi4 = lane >> 4;
        bf16x8 bf[8];
        const bf16x8* Bp = (const bf16x8*)(WextB + (size_t)ky * 4096);
#pragma unroll
        for (int i = 0; i < 8; i++) bf[i] = Bp[i * 64 + lane];
        const f32x4 zero = {0.f, 0.f, 0.f, 0.f};
#pragma unroll
        for (int mt = 0; mt < 2; mt++) {
            int mbase = m0 + mt * 16;
            bf16x8 af = *(const bf16x8*)(x1pb + ((size_t)(mbase + lo16) * 32 + hi4 * 8));
            f32x4 acc[8];
#pragma unroll
            for (int i = 0; i < 8; i++)
                acc[i] = __builtin_amdgcn_mfma_f32_16x16x32_bf16(af, bf[i], zero, 0, 0, 0);
#pragma unroll
            for (int tt = 0; tt < 4; tt++) {
#pragma unroll
                for (int j = 0; j < 4; j++) {
                    int n = mbase + hi4 * 4 + j;
                    unsigned lo = f2bf_bits(acc[tt][j]);
                    unsigned hi = f2bf_bits(acc[4 + tt][j]);
                    Au[(size_t)n * 832 + ky * 64 + tt * 16 + lo16] = lo | (hi << 16);
                }
            }
        }
    } else {
        int q = (blk - GEMM_BLKS) * 256 + t;
        if (q >= EE2) return;
        int4 rec = cscRec[q];
        int s = rec.x, d = rec.y;
        float inv = 0.5f / __uint_as_float(*mBits);
        float2 ps = ((const float2*)pos1)[s];
        float2 pd = ((const float2*)pos1)[d];
        float cx = fmaf(ps.x - pd.x, inv, 0.5f);
        float cy = fmaf(ps.y - pd.y, inv, 0.5f);
        unsigned out[16];
#pragma unroll
        for (int ky = 0; ky < 13; ky++) {
            int k0 = 2 * ky, k1 = 2 * ky + 1;
            float rlo = fmaxf(fmaf(cx, w1[k0], fmaf(cy, w1[25 + k0], b1[k0])), 0.f);
            float rhi = 1.f;
            if (k1 < 25) rhi = fmaxf(fmaf(cx, w1[k1], fmaf(cy, w1[25 + k1], b1[k1])), 0.f);
            out[ky] = f2bf_bits(rlo) | (f2bf_bits(rhi) << 16);
        }
        out[13] = (unsigned)rec.z;  // dest-order slot
        out[14] = 0u; out[15] = 0u;
        uint4* dst = r2q + (size_t)q * 4;
        dst[0] = make_uint4(out[0], out[1], out[2], out[3]);
        dst[1] = make_uint4(out[4], out[5], out[6], out[7]);
        dst[2] = make_uint4(out[8], out[9], out[10], out[11]);
        dst[3] = make_uint4(out[12], out[13], out[14], out[15]);
    }
}

// ---- conv2 phase 1: per-src streaming w/ next-edge prefetch; msg -> msgbuf[dstSlot] ----
__global__ __launch_bounds__(256) void conv2_msg(
    const unsigned* __restrict__ Au, const uint4* __restrict__ r2q,
    const int* __restrict__ rowptrS, unsigned short* __restrict__ msgbuf) {
    int t = threadIdx.x;
    int lane = t & 63;
    int s = __builtin_amdgcn_readfirstlane(blockIdx.x * 4 + (t >> 6));
    unsigned au[13];
    const unsigned* Ab = Au + (size_t)s * 832 + lane;
#pragma unroll
    for (int ky = 0; ky < 13; ky++) au[ky] = Ab[ky * 64];
    int r0 = rowptrS[s], r1 = rowptrS[s + 1];
    uint4 A0, B0, C0, D0;
    if (r0 < r1) {
        const uint4* p4 = r2q + (size_t)r0 * 4;
        A0 = p4[0]; B0 = p4[1]; C0 = p4[2]; D0 = p4[3];
    }
    for (int q = r0; q < r1; q++) {
        uint4 a = A0, b = B0, c = C0, dd = D0;
        if (q + 1 < r1) {
            const uint4* p4 = r2q + (size_t)(q + 1) * 4;
            A0 = p4[0]; B0 = p4[1]; C0 = p4[2]; D0 = p4[3];
        }
        unsigned rr[13] = {a.x, a.y, a.z, a.w, b.x, b.y, b.z, b.w, c.x, c.y, c.z, c.w, dd.x};
        unsigned dstSlot = dd.y;
        float m0 = 0.f, m1 = 0.f;
#pragma unroll
        for (int ky = 0; ky < 13; ky++) {
            unsigned rp = rr[ky];
            unsigned ua = au[ky];
            m0 = fmaf(__uint_as_float(rp << 16), __uint_as_float(ua << 16), m0);
            m1 = fmaf(__uint_as_float(rp & 0xFFFF0000u), __uint_as_float(ua & 0xFFFF0000u), m1);
        }
        msgbuf[(size_t)dstSlot * 64 + lane] = (unsigned short)f2bf_bits(m0 + m1);
    }
}

// ---- conv2 phase 2: per-dest STREAMING sum + fused x2 ----
__global__ __launch_bounds__(256) void conv2_fin(
    const unsigned short* __restrict__ msgbuf, const int* __restrict__ rowptrD,
    const float* __restrict__ x1p, const float* __restrict__ root2,
    const float* __restrict__ bias2, float* __restrict__ x2) {
    int t = threadIdx.x;
    int lane = t & 63;
    int n = blockIdx.x * 4 + (t >> 6);
    float Rr[32];
#pragma unroll
    for (int i = 0; i < 32; i++) Rr[i] = root2[i * 64 + lane];
    int r0 = rowptrD[n], r1 = rowptrD[n + 1];
    float acc = 0.f;
    for (int p = r0; p < r1; p++)
        acc += __uint_as_float((unsigned)msgbuf[(size_t)p * 64 + lane] << 16);
    float deg = fmaxf((float)(r1 - r0), 1.f);
    float xv = x1p[(size_t)n * 32 + (lane & 31)];
    float ra2 = bias2[lane];
#pragma unroll
    for (int i = 0; i < 32; i++) ra2 = fmaf(__shfl(xv, i, 64), Rr[i], ra2);
    x2[(size_t)n * 64 + lane] = elu_f(ra2 + acc / deg);
}

// ---- pool2 gather + fused xg accumulation (8-way sharded atomics) ----
__global__ __launch_bounds__(256) void pool2_gather(
    const float* __restrict__ x2, const int* __restrict__ rowptrC2,
    const int* __restrict__ memC2, const int* __restrict__ batch1,
    float* __restrict__ xgsumS, float* __restrict__ gcntS) {
    int t = threadIdx.x;
    int lane = t & 63;
    int n2 = blockIdx.x * 4 + (t >> 6);
    int r0 = rowptrC2[n2], r1 = rowptrC2[n2 + 1];
    float mx = -INFINITY;
    int bmax = INT_MIN;
    for (int p = r0; p < r1; p++) {
        int m = memC2[p];
        mx = fmaxf(mx, x2[(size_t)m * 64 + lane]);
        bmax = max(bmax, batch1[m]);
    }
    float v = (r0 < r1) ? mx : 0.f;
    int b = min(max(bmax, 0), BB - 1);
    int shard = n2 & 7;
    atomicAdd(xgsumS + ((size_t)shard * BB + b) * 64 + lane, v);
    if (lane == 0) atomicAdd(gcntS + shard * BB + b, 1.f);
}

// ---- head: sum shards -> mean -> fc1+elu -> fc2 -> log_softmax ----
__global__ __launch_bounds__(128) void head_kernel(
    const float* __restrict__ xgsumS, const float* __restrict__ gcntS,
    const float* __restrict__ fc1w, const float* __restrict__ fc1b,
    const float* __restrict__ fc2w, const float* __restrict__ fc2b,
    float* __restrict__ out) {
    int b = blockIdx.x;
    int t = threadIdx.x;
    __shared__ float xg[64];
    __shared__ float h[128];
    __shared__ float lg[NCLS];
    __shared__ float red[2];
    __shared__ float cntsh;
    float s = 0.f;
    if (t < 64) {
#pragma unroll
        for (int sh = 0; sh < 8; sh++) s += xgsumS[((size_t)sh * BB + b) * 64 + t];
    }
    if (t == 64) {
        float c = 0.f;
#pragma unroll
        for (int sh = 0; sh < 8; sh++) c += gcntS[sh * BB + b];
        cntsh = fmaxf(c, 1.f);
    }
    __syncthreads();
    if (t < 64) xg[t] = s / cntsh;
    __syncthreads();
    float a1 = fc1b[t];
    for (int i = 0; i < 64; i++) a1 = fmaf(xg[i], fc1w[i * 128 + t], a1);
    h[t] = elu_f(a1);
    __syncthreads();
    if (t < NCLS) {
        float a = fc2b[t];
        for (int j = 0; j < 128; j++) a = fmaf(h[j], fc2w[j * NCLS + t], a);
        lg[t] = a;
    }
    __syncthreads();
    if (t == 0) {
        float mx = lg[0];
        for (int i = 1; i < NCLS; i++) mx = fmaxf(mx, lg[i]);
        float se = 0.f;
        for (int i = 0; i < NCLS; i++) se += expf(lg[i] - mx);
        red[0] = mx;
        red[1] = logf(se);
    }
    __syncthreads();
    if (t < NCLS) out[(size_t)b * NCLS + t] = lg[t] - red[0] - red[1];
}

extern "C" void kernel_launch(void* const* d_in, const int* in_sizes, int n_in,
                              void* d_out, int out_size, void* d_ws, size_t ws_size,
                              hipStream_t stream) {
    const float* x = (const float*)d_in[0];
    const float* pos = (const float*)d_in[1];
    const float* edge_attr = (const float*)d_in[2];
    const int* ei = (const int*)d_in[3];
    const int* batch = (const int*)d_in[4];
    const int* cluster1 = (const int*)d_in[5];
    const int* ei2 = (const int*)d_in[6];
    const int* cluster2 = (const int*)d_in[7];
    const float* nn1_w1 = (const float*)d_in[8];
    const float* nn1_b1 = (const float*)d_in[9];
    const float* nn1_w2 = (const float*)d_in[10];
    const float* nn1_b2 = (const float*)d_in[11];
    const float* root1 = (const float*)d_in[12];
    const float* bias1 = (const float*)d_in[13];
    const float* nn2_w1 = (const float*)d_in[14];
    const float* nn2_b1 = (const float*)d_in[15];
    const float* nn2_w2 = (const float*)d_in[16];
    const float* nn2_b2 = (const float*)d_in[17];
    const float* root2 = (const float*)d_in[18];
    const float* bias2 = (const float*)d_in[19];
    const float* fc1w = (const float*)d_in[20];
    const float* fc1b = (const float*)d_in[21];
    const float* fc2w = (const float*)d_in[22];
    const float* fc2b = (const float*)d_in[23];

    float* ws = (float*)d_ws;
    // ---- workspace layout (float units; all blocks 16B-aligned) ----
    constexpr size_t OFF_DEG1 = 0;                                 // NN
    constexpr size_t OFF_DEGS = OFF_DEG1 + NN;                     // NN1
    constexpr size_t OFF_DEGD = OFF_DEGS + NN1;                    // NN1
    constexpr size_t OFF_DEGC1 = OFF_DEGD + NN1;                   // NN1
    constexpr size_t OFF_DEGC2 = OFF_DEGC1 + NN1;                  // NN2
    constexpr size_t OFF_XGS = OFF_DEGC2 + NN2;                    // 8*BB*64
    constexpr size_t OFF_GCS = OFF_XGS + (size_t)8 * BB * 64;      // 8*BB
    constexpr size_t OFF_MBITS = OFF_GCS + 8 * BB;                 // 4 (padded)
    constexpr size_t ZTOT = OFF_MBITS + 4;                         // zero region end
    constexpr size_t OFF_PART = ZTOT;                              // SBT
    constexpr size_t OFF_ROWPTR1 = OFF_PART + SBT;                 // NN+4
    constexpr size_t OFF_ROWPTRS = OFF_ROWPTR1 + NN + 4;           // NN1+4
    constexpr size_t OFF_ROWPTRD = OFF_ROWPTRS + NN1 + 4;          // NN1+4
    constexpr size_t OFF_ROWPTRC1 = OFF_ROWPTRD + NN1 + 4;         // NN1+4
    constexpr size_t OFF_ROWPTRC2 = OFF_ROWPTRC1 + NN1 + 4;        // NN2+4
    constexpr size_t OFF_SLOT1 = OFF_ROWPTRC2 + NN2 + 4;           // EE
    constexpr size_t OFF_SLOTS = OFF_SLOT1 + EE;                   // EE2
    constexpr size_t OFF_SLOTD = OFF_SLOTS + EE2;                  // EE2
    constexpr size_t OFF_SLOTC1 = OFF_SLOTD + EE2;                 // NN
    constexpr size_t OFF_SLOTC2 = OFF_SLOTC1 + NN;                 // NN1
    constexpr size_t OFF_CSCREC = OFF_SLOTC2 + NN1;                // EE2*4 (int4)
    constexpr size_t OFF_MEMC1 = OFF_CSCREC + (size_t)EE2 * 4;     // NN
    constexpr size_t OFF_MEMC2 = OFF_MEMC1 + NN;                   // NN1
    constexpr size_t OFF_X1 = OFF_MEMC2 + NN1;                     // NN*32
    constexpr size_t OFF_X1P = OFF_X1 + (size_t)NN * 32;           // NN1*32
    constexpr size_t OFF_X1PB = OFF_X1P + (size_t)NN1 * 32;        // NN1*16 (ushort NN1*32)
    constexpr size_t OFF_POS1 = OFF_X1PB + (size_t)NN1 * 16;       // NN1*2
    constexpr size_t OFF_BATCH1 = OFF_POS1 + (size_t)NN1 * 2;      // NN1
    constexpr size_t OFF_X2 = OFF_BATCH1 + NN1;                    // NN1*64
    constexpr size_t OFF_WEXTB = OFF_X2 + (size_t)NN1 * 64;        // 26624 (ushort 13*8*64*8)
    constexpr size_t OFF_UA = OFF_WEXTB + 26624;                   // union: eadj1 EE*4 / r2q EE2*16
    constexpr size_t UASZ = (size_t)EE2 * 16;                      // 2.62M >= EE*4
    constexpr size_t OFF_MSG = OFF_UA + UASZ;                      // EE2*32 (ushort EE2*64)
    constexpr size_t OFF_AU = OFF_MSG + (size_t)EE2 * 32;          // NN1*832 (uint)

    int* deg1 = (int*)(ws + OFF_DEG1);
    int* degS = (int*)(ws + OFF_DEGS);
    int* degD = (int*)(ws + OFF_DEGD);
    int* degC1 = (int*)(ws + OFF_DEGC1);
    int* degC2 = (int*)(ws + OFF_DEGC2);
    float* xgsumS = ws + OFF_XGS;
    float* gcntS = ws + OFF_GCS;
    unsigned* mBits = (unsigned*)(ws + OFF_MBITS);
    int* part = (int*)(ws + OFF_PART);
    int* rowptr1 = (int*)(ws + OFF_ROWPTR1);
    int* rowptrS = (int*)(ws + OFF_ROWPTRS);
    int* rowptrD = (int*)(ws + OFF_ROWPTRD);
    int* rowptrC1 = (int*)(ws + OFF_ROWPTRC1);
    int* rowptrC2 = (int*)(ws + OFF_ROWPTRC2);
    int* slot1 = (int*)(ws + OFF_SLOT1);
    int* slotS = (int*)(ws + OFF_SLOTS);
    int* slotD = (int*)(ws + OFF_SLOTD);
    int* slotC1 = (int*)(ws + OFF_SLOTC1);
    int* slotC2 = (int*)(ws + OFF_SLOTC2);
    int4* cscRec = (int4*)(ws + OFF_CSCREC);
    int* memC1 = (int*)(ws + OFF_MEMC1);
    int* memC2 = (int*)(ws + OFF_MEMC2);
    float* x1 = ws + OFF_X1;
    float* x1p = ws + OFF_X1P;
    unsigned short* x1pb = (unsigned short*)(ws + OFF_X1PB);
    float* pos1 = ws + OFF_POS1;
    int* batch1 = (int*)(ws + OFF_BATCH1);
    float* x2 = ws + OFF_X2;
    unsigned short* WextB = (unsigned short*)(ws + OFF_WEXTB);
    float4* eadj1 = (float4*)(ws + OFF_UA);
    uint4* r2q = (uint4*)(ws + OFF_UA);
    unsigned short* msgbuf = (unsigned short*)(ws + OFF_MSG);
    unsigned* Au = (unsigned*)(ws + OFF_AU);

    init_all<<<(int)((ZTOT + 255) / 256), 256, 0, stream>>>((int*)d_ws, (int)ZTOT);
    deg_count<<<EE / 256, 256, 0, stream>>>(ei, ei2, cluster1, cluster2,
                                            deg1, degS, degD, degC1, degC2,
                                            slot1, slotS, slotD, slotC1, slotC2);
    scan_partial<<<SBT, 256, 0, stream>>>(deg1, degS, degD, degC1, degC2, part);
    scan_apply<<<SBT, 256, 0, stream>>>(deg1, degS, degD, degC1, degC2, part,
                                        rowptr1, rowptrS, rowptrD, rowptrC1, rowptrC2);
    fill_csr<<<EE / 256, 256, 0, stream>>>(x, edge_attr, ei, ei2, cluster1, cluster2,
                                           rowptr1, rowptrS, rowptrD, rowptrC1, rowptrC2,
                                           slot1, slotS, slotD, slotC1, slotC2,
                                           eadj1, cscRec, memC1, memC2);
    conv1_gather<<<NN / 8, 256, 0, stream>>>(x, rowptr1, eadj1,
                                             nn1_w1, nn1_b1, nn1_w2, nn1_b2, root1, bias1, x1);
    pool1_gather<<<NN1 / 8, 256, 0, stream>>>(x1, pos, batch, rowptrC1, memC1,
                                              x1p, x1pb, pos1, batch1);
    cartmax_prep<<<CART_BLKS + PREP_BLKS, 256, 0, stream>>>(pos1, ei2, mBits,
                                                            nn2_w2, nn2_b2, WextB);
    gemm_r2<<<GEMM_BLKS + R2_BLKS, 256, 0, stream>>>(x1pb, WextB, Au,
                                                     cscRec, pos1, nn2_w1, nn2_b1,
                                                     mBits, r2q);
    conv2_msg<<<NN1 / 4, 256, 0, stream>>>(Au, r2q, rowptrS, msgbuf);
    conv2_fin<<<NN1 / 4, 256, 0, stream>>>(msgbuf, rowptrD, x1p, root2, bias2, x2);
    pool2_gather<<<NN2 / 4, 256, 0, stream>>>(x2, rowptrC2, memC2, batch1, xgsumS, gcntS);
    head_kernel<<<BB, 128, 0, stream>>>(xgsumS, gcntS, fc1w, fc1b, fc2w, fc2b,
                                        (float*)d_out);
}